// Round 1
// baseline (3908.694 us; speedup 1.0000x reference)
//
#include <hip/hip_runtime.h>
#include <hip/hip_bf16.h>
#include <cstdint>

#define B_ 256
#define D_ 128
#define T_ 512
#define H_ 256
#define C_ 10

using f32x4 = __attribute__((ext_vector_type(4))) float;
using s16x8 = __attribute__((ext_vector_type(8))) short;

__device__ __forceinline__ unsigned short f2bf(float f) {
    union { float f; uint32_t u; } a; a.f = f;
    uint32_t u = a.u;
    uint32_t r = (u + 0x7fffu + ((u >> 16) & 1u)) >> 16;   // RNE
    return (unsigned short)r;
}

__device__ __forceinline__ float sigm(float v) { return 1.0f / (1.0f + __expf(-v)); }

// ---------------------------------------------------------------------------
// Kernel 1: transpose x [B][D][T] f32  ->  xt [T][B][D] bf16
// grid: B * (T/64) blocks of 256 threads
// ---------------------------------------------------------------------------
__global__ void xt_kernel(const float* __restrict__ x, unsigned short* __restrict__ xt) {
    __shared__ unsigned short tile[128][66];
    const int b  = blockIdx.x >> 3;
    const int t0 = (blockIdx.x & 7) << 6;
    const int tid = threadIdx.x;
    const int j  = tid & 63;     // t within tile
    const int dq = tid >> 6;     // 0..3

#pragma unroll
    for (int it = 0; it < 32; ++it) {
        int d = it * 4 + dq;
        tile[d][j] = f2bf(x[(size_t)(b * D_ + d) * T_ + t0 + j]);
    }
    __syncthreads();

    uint32_t* xt32 = (uint32_t*)xt;
#pragma unroll
    for (int it = 0; it < 16; ++it) {
        int tl = it * 4 + dq;    // t within tile
        int dp = j;              // d-pair 0..63
        uint32_t lo = tile[2 * dp][tl];
        uint32_t hi = tile[2 * dp + 1][tl];
        xt32[(size_t)((t0 + tl) * B_ + b) * (D_ / 2) + dp] = lo | (hi << 16);
    }
}

// ---------------------------------------------------------------------------
// Kernel 2: persistent LSTM recurrence.
// 256 blocks = 16 batch-chunks (bc) x 16 H-slices (hc). 256 threads (4 waves).
// Wave w handles gate w (g,i,f,o). Per step: [16 x 384] @ [384 x 64] via MFMA.
// h exchanged via double-buffered global bf16 (packed u32) + per-group flags.
// ---------------------------------------------------------------------------
__global__ void __launch_bounds__(256) lstm_kernel(
    const float* __restrict__ Wgx, const float* __restrict__ Wix,
    const float* __restrict__ Wfx, const float* __restrict__ Wox,
    const float* __restrict__ Wgh, const float* __restrict__ Wih,
    const float* __restrict__ Wfh, const float* __restrict__ Woh,
    const float* __restrict__ bg,  const float* __restrict__ bi,
    const float* __restrict__ bf2, const float* __restrict__ bo,
    const unsigned short* __restrict__ xt,
    uint32_t* __restrict__ hbuf,
    int* __restrict__ flags,
    float* __restrict__ hfin)
{
    __shared__ __align__(16) unsigned short Wh_s[4][16][264]; // [gate][col][k], k over H
    __shared__ __align__(16) unsigned short Wx_s[4][16][136]; // [gate][col][k], k over D
    __shared__ __align__(16) unsigned short h_s[16][264];     // [brow][k]
    __shared__ __align__(16) unsigned short x_s[16][136];     // [brow][d]
    __shared__ float pre_s[4][16][17];                        // [gate][brow][unit]
    __shared__ float bias_s[4][16];

    const int tid  = threadIdx.x;
    const int bc   = blockIdx.x & 15;   // batch chunk (mod-16 -> XCD-friendly grouping)
    const int hc   = blockIdx.x >> 4;   // H slice
    const int wave = tid >> 6;
    const int lane = tid & 63;
    const int mrow = lane & 15;
    const int quad = lane >> 4;

    const float* Wh[4] = {Wgh, Wih, Wfh, Woh};
    const float* Wx[4] = {Wgx, Wix, Wfx, Wox};
    const float* bias[4] = {bg, bi, bf2, bo};

    // One-time: load W slices (transposed to [col][k]) into LDS as bf16.
#pragma unroll
    for (int g = 0; g < 4; ++g) {
        for (int it = 0; it < 16; ++it) {
            int idx = it * 256 + tid;          // 4096 = 256k x 16c
            int k = idx >> 4, c = idx & 15;
            Wh_s[g][c][k] = f2bf(Wh[g][(size_t)k * H_ + hc * 16 + c]);
        }
        for (int it = 0; it < 8; ++it) {
            int idx = it * 256 + tid;          // 2048 = 128k x 16c
            int k = idx >> 4, c = idx & 15;
            Wx_s[g][c][k] = f2bf(Wx[g][(size_t)k * H_ + hc * 16 + c]);
        }
    }
    if (tid < 64) bias_s[tid >> 4][tid & 15] = bias[tid >> 4][hc * 16 + (tid & 15)];
    __syncthreads();

    const int b_l = tid >> 4;   // 0..15 batch row within chunk
    const int u_l = tid & 15;   // 0..15 unit within slice
    float c_st = 0.0f, h_st = 0.0f;

    for (int t = 0; t < T_; ++t) {
        // x load for this step (independent of recurrence -> issue before spin)
        uint4 xv = *(const uint4*)(xt + ((size_t)(t * B_ + bc * 16 + b_l) * D_ + u_l * 8));

        if (t > 0) {
            if (tid < 16) {
                while (__hip_atomic_load(&flags[bc * 16 + tid], __ATOMIC_ACQUIRE,
                                         __HIP_MEMORY_SCOPE_AGENT) < t) {
                    __builtin_amdgcn_s_sleep(2);
                }
            }
            __syncthreads();
            // load h[t-1]: [16][128] packed u32
            const uint32_t* src = hbuf + (size_t)((t - 1) & 1) * B_ * (H_ / 2);
#pragma unroll
            for (int i = 0; i < 8; ++i) {
                int idx = i * 256 + tid;
                int row = idx >> 7, kp = idx & 127;
                uint32_t v = __hip_atomic_load(&src[(size_t)(bc * 16 + row) * (H_ / 2) + kp],
                                               __ATOMIC_RELAXED, __HIP_MEMORY_SCOPE_AGENT);
                *(uint32_t*)&h_s[row][2 * kp] = v;
            }
        }
        *(uint4*)&x_s[b_l][u_l * 8] = xv;
        __syncthreads();

        f32x4 acc = {0.f, 0.f, 0.f, 0.f};
        if (t > 0) {
#pragma unroll
            for (int kk = 0; kk < 8; ++kk) {
                s16x8 a  = *(const s16x8*)&h_s[mrow][kk * 32 + quad * 8];
                s16x8 bb = *(const s16x8*)&Wh_s[wave][mrow][kk * 32 + quad * 8];
                acc = __builtin_amdgcn_mfma_f32_16x16x32_bf16(a, bb, acc, 0, 0, 0);
            }
        }
#pragma unroll
        for (int kk = 0; kk < 4; ++kk) {
            s16x8 a  = *(const s16x8*)&x_s[mrow][kk * 32 + quad * 8];
            s16x8 bb = *(const s16x8*)&Wx_s[wave][mrow][kk * 32 + quad * 8];
            acc = __builtin_amdgcn_mfma_f32_16x16x32_bf16(a, bb, acc, 0, 0, 0);
        }

        // C layout: col = lane&15, row = quad*4 + r
#pragma unroll
        for (int r = 0; r < 4; ++r)
            pre_s[wave][quad * 4 + r][mrow] = acc[r];
        __syncthreads();

        float pg = pre_s[0][b_l][u_l] + bias_s[0][u_l];
        float pi = pre_s[1][b_l][u_l] + bias_s[1][u_l];
        float pf = pre_s[2][b_l][u_l] + bias_s[2][u_l];
        float po = pre_s[3][b_l][u_l] + bias_s[3][u_l];
        float gg = 2.0f * sigm(2.0f * pg) - 1.0f;   // tanh
        float ii = sigm(pi), ff = sigm(pf), oo = sigm(po);
        c_st = gg * ii + c_st * ff;
        float th = 2.0f * sigm(2.0f * c_st) - 1.0f; // tanh(c)
        h_st = th * oo;

        // pack pairs of bf16 h and publish
        uint32_t hb = f2bf(h_st);
        uint32_t other = (uint32_t)__shfl_down((int)hb, 1, 64);
        if ((tid & 1) == 0) {
            uint32_t val = hb | (other << 16);
            uint32_t* dst = hbuf + (size_t)(t & 1) * B_ * (H_ / 2);
            __hip_atomic_store(&dst[(size_t)(bc * 16 + b_l) * (H_ / 2) + hc * 8 + (u_l >> 1)],
                               val, __ATOMIC_RELAXED, __HIP_MEMORY_SCOPE_AGENT);
        }
        __syncthreads();   // drains vmem (s_waitcnt vmcnt(0) before barrier)
        if (tid == 0)
            __hip_atomic_store(&flags[bc * 16 + hc], t + 1, __ATOMIC_RELEASE,
                               __HIP_MEMORY_SCOPE_AGENT);
    }

    // final h (fp32) for the output projection
    hfin[(size_t)(bc * 16 + b_l) * H_ + hc * 16 + u_l] = h_st;
}

// ---------------------------------------------------------------------------
// Kernel 3: out[b][c] = h_final[b][:] @ W_ph[:, c] + b_p[c]
// ---------------------------------------------------------------------------
__global__ void proj_kernel(const float* __restrict__ hfin, const float* __restrict__ Wph,
                            const float* __restrict__ bp, float* __restrict__ out) {
    int gid = blockIdx.x * 256 + threadIdx.x;
    if (gid >= B_ * C_) return;
    int b = gid / C_, cc = gid % C_;
    float acc = bp[cc];
#pragma unroll 8
    for (int u = 0; u < H_; ++u)
        acc += hfin[(size_t)b * H_ + u] * Wph[(size_t)u * C_ + cc];
    out[gid] = acc;
}

// ---------------------------------------------------------------------------
extern "C" void kernel_launch(void* const* d_in, const int* in_sizes, int n_in,
                              void* d_out, int out_size, void* d_ws, size_t ws_size,
                              hipStream_t stream) {
    const float* x   = (const float*)d_in[0];
    const float* Wgx = (const float*)d_in[1];
    const float* Wix = (const float*)d_in[2];
    const float* Wfx = (const float*)d_in[3];
    const float* Wox = (const float*)d_in[4];
    const float* Wgh = (const float*)d_in[5];
    const float* Wih = (const float*)d_in[6];
    const float* Wfh = (const float*)d_in[7];
    const float* Woh = (const float*)d_in[8];
    const float* bg  = (const float*)d_in[9];
    const float* bi  = (const float*)d_in[10];
    const float* bf2 = (const float*)d_in[11];
    const float* bo  = (const float*)d_in[12];
    const float* Wph = (const float*)d_in[13];
    const float* bp  = (const float*)d_in[14];

    char* ws = (char*)d_ws;
    // layout: flags (1 KiB) | hbuf 2*B*H/2 u32 (256 KiB) | hfin B*H f32 (256 KiB) | xt T*B*D bf16 (32 MiB)
    int*            flags = (int*)ws;
    uint32_t*       hbuf  = (uint32_t*)(ws + 1024);
    float*          hfin  = (float*)(ws + 1024 + 2 * B_ * (H_ / 2) * 4);
    unsigned short* xt    = (unsigned short*)(ws + 1024 + 2 * B_ * (H_ / 2) * 4 + B_ * H_ * 4);

    hipMemsetAsync(flags, 0, 16 * 16 * sizeof(int), stream);

    xt_kernel<<<B_ * (T_ / 64), 256, 0, stream>>>(x, xt);

    lstm_kernel<<<256, 256, 0, stream>>>(Wgx, Wix, Wfx, Wox, Wgh, Wih, Wfh, Woh,
                                         bg, bi, bf2, bo, xt, hbuf, flags, hfin);

    proj_kernel<<<(B_ * C_ + 255) / 256, 256, 0, stream>>>(hfin, Wph, bp, (float*)d_out);
}

// Round 2
// 1196.619 us; speedup vs baseline: 3.2664x; 3.2664x over previous
//
#include <hip/hip_runtime.h>
#include <hip/hip_bf16.h>
#include <cstdint>

#define B_ 256
#define D_ 128
#define T_ 512
#define H_ 256
#define C_ 10

using f32x4 = __attribute__((ext_vector_type(4))) float;
using s16x8 = __attribute__((ext_vector_type(8))) short;

__device__ __forceinline__ unsigned short f2bf(float f) {
    union { float f; uint32_t u; } a; a.f = f;
    uint32_t u = a.u;
    uint32_t r = (u + 0x7fffu + ((u >> 16) & 1u)) >> 16;   // RNE
    return (unsigned short)r;
}

__device__ __forceinline__ float sigm(float v) { return 1.0f / (1.0f + __expf(-v)); }

// ---------------------------------------------------------------------------
// Kernel 1: transpose x [B][D][T] f32  ->  xt [T][B][D] bf16
// ---------------------------------------------------------------------------
__global__ void xt_kernel(const float* __restrict__ x, unsigned short* __restrict__ xt) {
    __shared__ unsigned short tile[128][66];
    const int b  = blockIdx.x >> 3;
    const int t0 = (blockIdx.x & 7) << 6;
    const int tid = threadIdx.x;
    const int j  = tid & 63;
    const int dq = tid >> 6;

#pragma unroll
    for (int it = 0; it < 32; ++it) {
        int d = it * 4 + dq;
        tile[d][j] = f2bf(x[(size_t)(b * D_ + d) * T_ + t0 + j]);
    }
    __syncthreads();

    uint32_t* xt32 = (uint32_t*)xt;
#pragma unroll
    for (int it = 0; it < 16; ++it) {
        int tl = it * 4 + dq;
        int dp = j;
        uint32_t lo = tile[2 * dp][tl];
        uint32_t hi = tile[2 * dp + 1][tl];
        xt32[(size_t)((t0 + tl) * B_ + b) * (D_ / 2) + dp] = lo | (hi << 16);
    }
}

// ---------------------------------------------------------------------------
// Kernel 2: persistent LSTM recurrence.
// 256 blocks = 16 batch-chunks (bc) x 16 H-slices (hc), 256 threads (4 waves).
// Wave w = gate w. Per step: [16 x 384] @ [384 x 64] via mfma_16x16x32_bf16.
// h exchanged via double-buffered MALL-resident buffer, RELAXED agent atomics
// only (no acquire/release -> no buffer_inv / buffer_wbl2 on the hot path).
// Ordering: __syncthreads() drains vmcnt(0) before the flag store.
// ---------------------------------------------------------------------------
__global__ void __launch_bounds__(256) lstm_kernel(
    const float* __restrict__ Wgx, const float* __restrict__ Wix,
    const float* __restrict__ Wfx, const float* __restrict__ Wox,
    const float* __restrict__ Wgh, const float* __restrict__ Wih,
    const float* __restrict__ Wfh, const float* __restrict__ Woh,
    const float* __restrict__ bg,  const float* __restrict__ bi,
    const float* __restrict__ bf2, const float* __restrict__ bo,
    const unsigned short* __restrict__ xt,
    uint64_t* __restrict__ hbuf,
    int* __restrict__ flags,
    float* __restrict__ hfin)
{
    __shared__ __align__(16) unsigned short Wh_s[4][16][264];
    __shared__ __align__(16) unsigned short Wx_s[4][16][136];
    __shared__ __align__(16) unsigned short h_s[16][264];
    __shared__ __align__(16) unsigned short x_s[16][136];
    __shared__ float pre_s[4][16][17];
    __shared__ float bias_s[4][16];

    const int tid  = threadIdx.x;
    const int bc   = blockIdx.x & 15;
    const int hc   = blockIdx.x >> 4;
    const int wave = tid >> 6;
    const int lane = tid & 63;
    const int mrow = lane & 15;
    const int quad = lane >> 4;

    const float* Wh[4] = {Wgh, Wih, Wfh, Woh};
    const float* Wx[4] = {Wgx, Wix, Wfx, Wox};
    const float* bias[4] = {bg, bi, bf2, bo};

#pragma unroll
    for (int g = 0; g < 4; ++g) {
        for (int it = 0; it < 16; ++it) {
            int idx = it * 256 + tid;
            int k = idx >> 4, c = idx & 15;
            Wh_s[g][c][k] = f2bf(Wh[g][(size_t)k * H_ + hc * 16 + c]);
        }
        for (int it = 0; it < 8; ++it) {
            int idx = it * 256 + tid;
            int k = idx >> 4, c = idx & 15;
            Wx_s[g][c][k] = f2bf(Wx[g][(size_t)k * H_ + hc * 16 + c]);
        }
    }
    if (tid < 64) bias_s[tid >> 4][tid & 15] = bias[tid >> 4][hc * 16 + (tid & 15)];
    __syncthreads();

    const int b_l = tid >> 4;
    const int u_l = tid & 15;
    float c_st = 0.0f, h_st = 0.0f;

    // prefetch x for t=0
    uint4 xv = *(const uint4*)(xt + ((size_t)(0 * B_ + bc * 16 + b_l) * D_ + u_l * 8));

    for (int t = 0; t < T_; ++t) {
        // publish this step's x into LDS (xv prefetched last iteration)
        *(uint4*)&x_s[b_l][u_l * 8] = xv;

        if (t > 0 && tid < 16) {
            while (__hip_atomic_load(&flags[bc * 16 + tid], __ATOMIC_RELAXED,
                                     __HIP_MEMORY_SCOPE_AGENT) < t) {
                __builtin_amdgcn_s_sleep(1);
            }
        }
        __syncthreads();   // A: orders spin; publishes x_s

        // prefetch next step's x (arrives long before it's needed)
        if (t + 1 < T_)
            xv = *(const uint4*)(xt + ((size_t)((t + 1) * B_ + bc * 16 + b_l) * D_ + u_l * 8));

        // issue h[t-1] global loads first (MALL latency), overlap with x-MFMAs
        uint64_t hv[4];
        if (t > 0) {
            const uint64_t* src = hbuf + (size_t)((t - 1) & 1) * B_ * (H_ / 4);
#pragma unroll
            for (int i = 0; i < 4; ++i) {
                int idx = i * 256 + tid;
                int row = idx >> 6, kp = idx & 63;
                hv[i] = __hip_atomic_load(&src[(size_t)(bc * 16 + row) * (H_ / 4) + kp],
                                          __ATOMIC_RELAXED, __HIP_MEMORY_SCOPE_AGENT);
            }
        }

        f32x4 accx = {0.f, 0.f, 0.f, 0.f};
#pragma unroll
        for (int kk = 0; kk < 4; ++kk) {
            s16x8 a  = *(const s16x8*)&x_s[mrow][kk * 32 + quad * 8];
            s16x8 bb = *(const s16x8*)&Wx_s[wave][mrow][kk * 32 + quad * 8];
            accx = __builtin_amdgcn_mfma_f32_16x16x32_bf16(a, bb, accx, 0, 0, 0);
        }

        if (t > 0) {
#pragma unroll
            for (int i = 0; i < 4; ++i) {
                int idx = i * 256 + tid;
                int row = idx >> 6, kp = idx & 63;
                *(uint64_t*)&h_s[row][kp * 4] = hv[i];
            }
        }
        __syncthreads();   // B: h_s ready

        f32x4 acc0 = {0.f, 0.f, 0.f, 0.f};
        f32x4 acc1 = {0.f, 0.f, 0.f, 0.f};
        if (t > 0) {
#pragma unroll
            for (int j = 0; j < 4; ++j) {
                s16x8 a  = *(const s16x8*)&h_s[mrow][(2 * j) * 32 + quad * 8];
                s16x8 bb = *(const s16x8*)&Wh_s[wave][mrow][(2 * j) * 32 + quad * 8];
                acc0 = __builtin_amdgcn_mfma_f32_16x16x32_bf16(a, bb, acc0, 0, 0, 0);
                s16x8 a2  = *(const s16x8*)&h_s[mrow][(2 * j + 1) * 32 + quad * 8];
                s16x8 bb2 = *(const s16x8*)&Wh_s[wave][mrow][(2 * j + 1) * 32 + quad * 8];
                acc1 = __builtin_amdgcn_mfma_f32_16x16x32_bf16(a2, bb2, acc1, 0, 0, 0);
            }
        }

#pragma unroll
        for (int r = 0; r < 4; ++r)
            pre_s[wave][quad * 4 + r][mrow] = accx[r] + acc0[r] + acc1[r];
        __syncthreads();   // C: pre-activations ready

        float pg = pre_s[0][b_l][u_l] + bias_s[0][u_l];
        float pi = pre_s[1][b_l][u_l] + bias_s[1][u_l];
        float pf = pre_s[2][b_l][u_l] + bias_s[2][u_l];
        float po = pre_s[3][b_l][u_l] + bias_s[3][u_l];
        float gg = 2.0f * sigm(2.0f * pg) - 1.0f;   // tanh
        float ii = sigm(pi), ff = sigm(pf), oo = sigm(po);
        c_st = gg * ii + c_st * ff;
        float th = 2.0f * sigm(2.0f * c_st) - 1.0f; // tanh(c)
        h_st = th * oo;

        // pack 4 units into a u64 and publish (32 stores/block)
        uint32_t hb = f2bf(h_st);
        uint32_t p = hb | ((uint32_t)__shfl_down((int)hb, 1, 64) << 16);
        uint32_t q = (uint32_t)__shfl_down((int)p, 2, 64);
        if ((tid & 3) == 0) {
            uint64_t val = ((uint64_t)q << 32) | (uint64_t)p;
            uint64_t* dst = hbuf + (size_t)(t & 1) * B_ * (H_ / 4);
            __hip_atomic_store(&dst[(size_t)(bc * 16 + b_l) * (H_ / 4) + hc * 4 + (u_l >> 2)],
                               val, __ATOMIC_RELAXED, __HIP_MEMORY_SCOPE_AGENT);
        }
        __syncthreads();   // D: s_waitcnt vmcnt(0) drain -> h stores complete at MALL
        if (tid == 0)
            __hip_atomic_store(&flags[bc * 16 + hc], t + 1, __ATOMIC_RELAXED,
                               __HIP_MEMORY_SCOPE_AGENT);
    }

    hfin[(size_t)(bc * 16 + b_l) * H_ + hc * 16 + u_l] = h_st;
}

// ---------------------------------------------------------------------------
// Kernel 3: out = h_final @ W_ph + b_p
// ---------------------------------------------------------------------------
__global__ void proj_kernel(const float* __restrict__ hfin, const float* __restrict__ Wph,
                            const float* __restrict__ bp, float* __restrict__ out) {
    int gid = blockIdx.x * 256 + threadIdx.x;
    if (gid >= B_ * C_) return;
    int b = gid / C_, cc = gid % C_;
    float acc = bp[cc];
#pragma unroll 8
    for (int u = 0; u < H_; ++u)
        acc += hfin[(size_t)b * H_ + u] * Wph[(size_t)u * C_ + cc];
    out[gid] = acc;
}

// ---------------------------------------------------------------------------
extern "C" void kernel_launch(void* const* d_in, const int* in_sizes, int n_in,
                              void* d_out, int out_size, void* d_ws, size_t ws_size,
                              hipStream_t stream) {
    const float* x   = (const float*)d_in[0];
    const float* Wgx = (const float*)d_in[1];
    const float* Wix = (const float*)d_in[2];
    const float* Wfx = (const float*)d_in[3];
    const float* Wox = (const float*)d_in[4];
    const float* Wgh = (const float*)d_in[5];
    const float* Wih = (const float*)d_in[6];
    const float* Wfh = (const float*)d_in[7];
    const float* Woh = (const float*)d_in[8];
    const float* bg  = (const float*)d_in[9];
    const float* bi  = (const float*)d_in[10];
    const float* bf2 = (const float*)d_in[11];
    const float* bo  = (const float*)d_in[12];
    const float* Wph = (const float*)d_in[13];
    const float* bp  = (const float*)d_in[14];

    char* ws = (char*)d_ws;
    int*            flags = (int*)ws;
    uint64_t*       hbuf  = (uint64_t*)(ws + 1024);
    float*          hfin  = (float*)(ws + 1024 + 2 * B_ * (H_ / 4) * 8);
    unsigned short* xt    = (unsigned short*)(ws + 1024 + 2 * B_ * (H_ / 4) * 8 + B_ * H_ * 4);

    hipMemsetAsync(flags, 0, 16 * 16 * sizeof(int), stream);

    xt_kernel<<<B_ * (T_ / 64), 256, 0, stream>>>(x, xt);

    lstm_kernel<<<256, 256, 0, stream>>>(Wgx, Wix, Wfx, Wox, Wgh, Wih, Wfh, Woh,
                                         bg, bi, bf2, bo, xt, hbuf, flags, hfin);

    proj_kernel<<<(B_ * C_ + 255) / 256, 256, 0, stream>>>(hfin, Wph, bp, (float*)d_out);
}